// Round 5
// baseline (338.537 us; speedup 1.0000x reference)
//
#include <hip/hip_runtime.h>
#include <math.h>

// Problem dims
#define AA 256
#define HH 1024
#define CC 1024
#define NN 8192
#define MM 4096

// ws layout (float offsets).
#define WS_G      0
#define WS_GAMMA  1
#define WS_SR     2
#define WS_SW     3
#define GI_OFF    4
#define GH_OFF    (GI_OFF + 3*CC)          // 3076
#define TR_OFF    (GH_OFF + 3*CC)          // 6148
#define TW_OFF    (TR_OFF + NN)            // 14340
#define P_OFF     (TW_OFF + NN)            // 22532; partials: 512 x 4096 floats = 8 MB

__device__ __forceinline__ float wave_reduce(float v) {
    #pragma unroll
    for (int o = 32; o > 0; o >>= 1) v += __shfl_down(v, o);
    return v;
}

// K1: gi[row] = dot(x, W_ih[row]) + b_ih; gh[row] = dot(h_prev, W_hh[row]) + b_hh.
// Wave-per-row: 768 blocks x 256 threads (4 waves = 4 rows/block). 9 independent
// float4 loads per lane, shuffle-only reduce, no LDS.
__global__ __launch_bounds__(256) void k_gru_gates(
    const float* __restrict__ action, const float* __restrict__ hidden,
    const float* __restrict__ W_ih, const float* __restrict__ W_hh,
    const float* __restrict__ b_ih, const float* __restrict__ b_hh,
    const float* __restrict__ hprev, float* __restrict__ ws)
{
    const int t = threadIdx.x;
    const int wid = t >> 6, lane = t & 63;
    const int row = blockIdx.x * 4 + wid;

    const float4* __restrict__ Wih4 = (const float4*)W_ih + (size_t)row * 320; // 1280/4
    const float4* __restrict__ Whh4 = (const float4*)W_hh + (size_t)row * 256; // 1024/4
    const float4* __restrict__ act4 = (const float4*)action;  // 64 float4
    const float4* __restrict__ hid4 = (const float4*)hidden;  // 256 float4
    const float4* __restrict__ hp4  = (const float4*)hprev;   // 256 float4

    float4 a[5], b[4], xa[5], xb[4];
    #pragma unroll
    for (int j = 0; j < 5; ++j) a[j] = Wih4[lane + 64 * j];
    #pragma unroll
    for (int j = 0; j < 4; ++j) b[j] = Whh4[lane + 64 * j];
    xa[0] = act4[lane];
    #pragma unroll
    for (int j = 1; j < 5; ++j) xa[j] = hid4[lane + 64 * (j - 1)];
    #pragma unroll
    for (int j = 0; j < 4; ++j) xb[j] = hp4[lane + 64 * j];

    float si = 0.0f, sh = 0.0f;
    #pragma unroll
    for (int j = 0; j < 5; ++j)
        si += a[j].x * xa[j].x + a[j].y * xa[j].y + a[j].z * xa[j].z + a[j].w * xa[j].w;
    #pragma unroll
    for (int j = 0; j < 4; ++j)
        sh += b[j].x * xb[j].x + b[j].y * xb[j].y + b[j].z * xb[j].z + b[j].w * xb[j].w;

    si = wave_reduce(si);
    sh = wave_reduce(sh);
    if (lane == 0) {
        ws[GI_OFF + row] = si + b_ih[row];
        ws[GH_OFF + row] = sh + b_hh[row];
    }
}

// K2 (1 block, 1024 threads): GRU combine -> h; write hidden output;
// g = sigmoid(h.W_gate + b), gamma = softplus(h.W_gamma + b). Also zero S_r/S_w
// (ws is 0xAA-poisoned before every launch; kernel boundary publishes the zeros).
__global__ __launch_bounds__(1024) void k_gru_combine(
    const float* __restrict__ hprev,
    const float* __restrict__ W_gate, const float* __restrict__ b_gate,
    const float* __restrict__ W_gamma, const float* __restrict__ b_gamma,
    float* __restrict__ ws, float* __restrict__ d_out)
{
    const int c = threadIdx.x;
    if (c == 1) ws[WS_SR] = 0.0f;
    if (c == 2) ws[WS_SW] = 0.0f;
    const float* gi = ws + GI_OFF;
    const float* gh = ws + GH_OFF;
    const float r = 1.0f / (1.0f + expf(-(gi[c] + gh[c])));
    const float z = 1.0f / (1.0f + expf(-(gi[CC + c] + gh[CC + c])));
    const float n = tanhf(gi[2 * CC + c] + r * gh[2 * CC + c]);
    const float h = (1.0f - z) * n + z * hprev[c];
    d_out[MM + 2 * NN + c] = h;   // new_controller_hidden section

    float vg = h * W_gate[c];
    float vm = h * W_gamma[c];
    vg = wave_reduce(vg);
    vm = wave_reduce(vm);
    __shared__ float rg[16], rm[16];
    const int wid = c >> 6;
    if ((c & 63) == 0) { rg[wid] = vg; rm[wid] = vm; }
    __syncthreads();
    if (c == 0) {
        float sg = 0.0f, sm = 0.0f;
        #pragma unroll
        for (int i = 0; i < 16; ++i) { sg += rg[i]; sm += rm[i]; }
        sg += b_gate[0];
        sm += b_gamma[0];
        ws[WS_G] = 1.0f / (1.0f + expf(-sg));
        ws[WS_GAMMA] = (sm > 20.0f) ? sm : log1pf(expf(sm));
    }
}

// K3: the 128 MB pass. Grid (4, 512), block 256 = 4 waves. Block (bx,by) covers
// float4-cols [bx*256,+256) x rows [by*16,+16). 2048 blocks x 4 waves = 8192
// waves = 32 waves/CU (the max) -- per-CU memory concurrency scales with
// resident waves, which R4 showed is the binding resource (per-thread depth
// 8->16 was neutral). __launch_bounds__(256,8) pins VGPR<=64 so all 8 waves/SIMD
// fit. Each thread: 16 rows in two 8-deep groups. Weights t_i=(g+(1-g)p_i)^gamma
// inline (cosine-sim weights identically 1.0: softmax over size-1 axis;
// circular-conv scalar cancels in sharpen). bx==0 blocks with even by emit
// t_r/t_w + S atomics for their 32-row span. Partials per (by,col).
__global__ __launch_bounds__(256, 8) void k_readvec(
    const float* __restrict__ memory,
    const float* __restrict__ prev_r, const float* __restrict__ prev_w,
    float* __restrict__ ws)
{
    __shared__ float tch[16];
    const int t = threadIdx.x;
    const int bx = blockIdx.x;      // 0..3
    const int by = blockIdx.y;      // 0..511
    const int row0 = by * 16;

    if (t < 16) {
        const float g = ws[WS_G];
        const float gamma = ws[WS_GAMMA];
        const float tr = powf(g + (1.0f - g) * prev_r[row0 + t], gamma);
        tch[t] = tr;
        if (bx == 0) {
            const float tw = powf(g + (1.0f - g) * prev_w[row0 + t], gamma);
            ws[TR_OFF + row0 + t] = tr;
            ws[TW_OFF + row0 + t] = tw;
            float sr = tr, sw = tw;
            #pragma unroll
            for (int o = 8; o > 0; o >>= 1) {
                sr += __shfl_down(sr, o);
                sw += __shfl_down(sw, o);
            }
            if (t == 0) { atomicAdd(&ws[WS_SR], sr); atomicAdd(&ws[WS_SW], sw); }
        }
    }
    __syncthreads();

    const int c4 = bx * 256 + t;    // float4 column, 0..1023
    const float4* __restrict__ mem4 = (const float4*)memory + (size_t)row0 * 1024 + c4;
    float ax = 0.0f, ay = 0.0f, az = 0.0f, aw = 0.0f;
    #pragma unroll
    for (int grp = 0; grp < 2; ++grp) {
        float4 m[8];
        #pragma unroll
        for (int j = 0; j < 8; ++j)
            m[j] = mem4[(size_t)(grp * 8 + j) * 1024];
        #pragma unroll
        for (int j = 0; j < 8; ++j) {
            const float w = tch[grp * 8 + j];
            ax += w * m[j].x; ay += w * m[j].y; az += w * m[j].z; aw += w * m[j].w;
        }
    }
    float4 acc; acc.x = ax; acc.y = ay; acc.z = az; acc.w = aw;
    ((float4*)(ws + P_OFF))[(size_t)by * 1024 + c4] = acc;
}

// K4: finalize. Blocks 0..15: read_vector[col] = sum_yb P[yb][col] / S_r
// (coalesced at every yb iteration, 4-way accumulator ILP over 512 partials).
// Blocks 16..79: weight outputs t/S.
__global__ __launch_bounds__(256) void k_finalize(
    const float* __restrict__ ws, float* __restrict__ d_out)
{
    const int t = threadIdx.x, b = blockIdx.x;
    if (b < 16) {
        const int col = b * 256 + t;
        const float* __restrict__ P = ws + P_OFF;
        float s0 = 0.0f, s1 = 0.0f, s2 = 0.0f, s3 = 0.0f;
        #pragma unroll 8
        for (int yb = 0; yb < 512; yb += 4) {
            s0 += P[(size_t)(yb + 0) * 4096 + col];
            s1 += P[(size_t)(yb + 1) * 4096 + col];
            s2 += P[(size_t)(yb + 2) * 4096 + col];
            s3 += P[(size_t)(yb + 3) * 4096 + col];
        }
        d_out[col] = (s0 + s1 + s2 + s3) / ws[WS_SR];
    } else {
        const int idx = (b - 16) * 256 + t;   // 0..16383
        d_out[MM + idx] = (idx < NN) ? ws[TR_OFF + idx] / ws[WS_SR]
                                     : ws[TW_OFF + idx - NN] / ws[WS_SW];
    }
}

extern "C" void kernel_launch(void* const* d_in, const int* in_sizes, int n_in,
                              void* d_out, int out_size, void* d_ws, size_t ws_size,
                              hipStream_t stream)
{
    const float* action = (const float*)d_in[0];
    const float* hidden = (const float*)d_in[1];
    const float* prev_r = (const float*)d_in[2];
    const float* prev_w = (const float*)d_in[3];
    const float* hprev  = (const float*)d_in[4];   // prev_controller_hidden
    const float* memory = (const float*)d_in[5];
    const float* W_ih   = (const float*)d_in[6];
    const float* W_hh   = (const float*)d_in[7];
    const float* b_ih   = (const float*)d_in[8];
    const float* b_hh   = (const float*)d_in[9];
    // d_in[10..19] provably unused: softmax over size-1 axis == 1 (kills W_read/W_write
    // and the memory-norm pass), circular-conv scalar cancels in sharpen (kills W_shift),
    // memory write is discarded (kills W_add/W_erase).
    const float* W_gamma = (const float*)d_in[20];
    const float* b_gamma = (const float*)d_in[21];
    const float* W_gate  = (const float*)d_in[22];
    const float* b_gate  = (const float*)d_in[23];

    float* ws  = (float*)d_ws;
    float* out = (float*)d_out;

    hipLaunchKernelGGL(k_gru_gates, dim3(3 * CC / 4), dim3(256), 0, stream,
                       action, hidden, W_ih, W_hh, b_ih, b_hh, hprev, ws);
    hipLaunchKernelGGL(k_gru_combine, dim3(1), dim3(1024), 0, stream,
                       hprev, W_gate, b_gate, W_gamma, b_gamma, ws, out);
    hipLaunchKernelGGL(k_readvec, dim3(4, 512), dim3(256), 0, stream,
                       memory, prev_r, prev_w, ws);
    hipLaunchKernelGGL(k_finalize, dim3(80), dim3(256), 0, stream,
                       ws, out);
}

// Round 7
// 312.800 us; speedup vs baseline: 1.0823x; 1.0823x over previous
//
#include <hip/hip_runtime.h>
#include <math.h>

// Problem dims
#define AA 256
#define HH 1024
#define CC 1024
#define NN 8192
#define MM 4096

// ws layout (float offsets).
#define WS_G      0
#define WS_GAMMA  1
#define GI_OFF    4
#define GH_OFF    (GI_OFF + 3*CC)          // 3076
#define WN_OFF    (GH_OFF + 3*CC)          // 6148: normalized read weights (8192)
#define P_OFF     (WN_OFF + NN)            // 14340; partials: 256 x 4096 floats = 4 MB

// Native vector type for __builtin_nontemporal_load (HIP's float4 is a class
// type the builtin rejects; this lowers to the same global_load_dwordx4 + nt).
typedef float nt_f4 __attribute__((ext_vector_type(4)));

__device__ __forceinline__ float wave_reduce(float v) {
    #pragma unroll
    for (int o = 32; o > 0; o >>= 1) v += __shfl_down(v, o);
    return v;
}

// K1: gi[row] = dot(x, W_ih[row]) + b_ih; gh[row] = dot(h_prev, W_hh[row]) + b_hh.
// Wave-per-row: 768 blocks x 256 threads (4 waves = 4 rows/block). 9 independent
// float4 loads per lane, shuffle-only reduce, no LDS. (Unchanged since R2 - known good.)
__global__ __launch_bounds__(256) void k_gru_gates(
    const float* __restrict__ action, const float* __restrict__ hidden,
    const float* __restrict__ W_ih, const float* __restrict__ W_hh,
    const float* __restrict__ b_ih, const float* __restrict__ b_hh,
    const float* __restrict__ hprev, float* __restrict__ ws)
{
    const int t = threadIdx.x;
    const int wid = t >> 6, lane = t & 63;
    const int row = blockIdx.x * 4 + wid;

    const float4* __restrict__ Wih4 = (const float4*)W_ih + (size_t)row * 320; // 1280/4
    const float4* __restrict__ Whh4 = (const float4*)W_hh + (size_t)row * 256; // 1024/4
    const float4* __restrict__ act4 = (const float4*)action;  // 64 float4
    const float4* __restrict__ hid4 = (const float4*)hidden;  // 256 float4
    const float4* __restrict__ hp4  = (const float4*)hprev;   // 256 float4

    float4 a[5], b[4], xa[5], xb[4];
    #pragma unroll
    for (int j = 0; j < 5; ++j) a[j] = Wih4[lane + 64 * j];
    #pragma unroll
    for (int j = 0; j < 4; ++j) b[j] = Whh4[lane + 64 * j];
    xa[0] = act4[lane];
    #pragma unroll
    for (int j = 1; j < 5; ++j) xa[j] = hid4[lane + 64 * (j - 1)];
    #pragma unroll
    for (int j = 0; j < 4; ++j) xb[j] = hp4[lane + 64 * j];

    float si = 0.0f, sh = 0.0f;
    #pragma unroll
    for (int j = 0; j < 5; ++j)
        si += a[j].x * xa[j].x + a[j].y * xa[j].y + a[j].z * xa[j].z + a[j].w * xa[j].w;
    #pragma unroll
    for (int j = 0; j < 4; ++j)
        sh += b[j].x * xb[j].x + b[j].y * xb[j].y + b[j].z * xb[j].z + b[j].w * xb[j].w;

    si = wave_reduce(si);
    sh = wave_reduce(sh);
    if (lane == 0) {
        ws[GI_OFF + row] = si + b_ih[row];
        ws[GH_OFF + row] = sh + b_hh[row];
    }
}

// K2 (1 block, 1024 threads): GRU combine -> h -> hidden output; g = sigmoid(h.W_gate+b),
// gamma = softplus(h.W_gamma+b); then the ENTIRE weight path in-block (no atomics):
// t_i = (g + (1-g)*prev_i)^gamma  [cosine-sim weights are identically 1.0: softmax over a
// size-1 axis; circular-conv scalar cancels in sharpen], S = block-reduce(t),
// weight outputs = t/S written directly to d_out, normalized read weights to ws for K3.
__global__ __launch_bounds__(1024) void k_gru_combine(
    const float* __restrict__ hprev,
    const float* __restrict__ prev_r, const float* __restrict__ prev_w,
    const float* __restrict__ W_gate, const float* __restrict__ b_gate,
    const float* __restrict__ W_gamma, const float* __restrict__ b_gamma,
    float* __restrict__ ws, float* __restrict__ d_out)
{
    const int c = threadIdx.x;
    __shared__ float rg[16], rm[16], bc[4];

    // ---- GRU combine ----
    const float* gi = ws + GI_OFF;
    const float* gh = ws + GH_OFF;
    const float r = 1.0f / (1.0f + expf(-(gi[c] + gh[c])));
    const float z = 1.0f / (1.0f + expf(-(gi[CC + c] + gh[CC + c])));
    const float n = tanhf(gi[2 * CC + c] + r * gh[2 * CC + c]);
    const float h = (1.0f - z) * n + z * hprev[c];
    d_out[MM + 2 * NN + c] = h;   // new_controller_hidden section

    // ---- g, gamma ----
    float vg = wave_reduce(h * W_gate[c]);
    float vm = wave_reduce(h * W_gamma[c]);
    const int wid = c >> 6;
    if ((c & 63) == 0) { rg[wid] = vg; rm[wid] = vm; }
    __syncthreads();
    if (c == 0) {
        float sg = 0.0f, sm = 0.0f;
        #pragma unroll
        for (int i = 0; i < 16; ++i) { sg += rg[i]; sm += rm[i]; }
        sg += b_gate[0];
        sm += b_gamma[0];
        const float g = 1.0f / (1.0f + expf(-sg));
        const float gamma = (sm > 20.0f) ? sm : log1pf(expf(sm));
        ws[WS_G] = g; ws[WS_GAMMA] = gamma;
        bc[0] = g; bc[1] = gamma;
    }
    __syncthreads();
    const float g = bc[0], gamma = bc[1];

    // ---- weights: 8 rows per thread, coalesced (row = c + 1024*k) ----
    float tr[8], tw[8];
    float sr = 0.0f, sw = 0.0f;
    #pragma unroll
    for (int k = 0; k < 8; ++k) {
        const int row = c + 1024 * k;
        tr[k] = powf(g + (1.0f - g) * prev_r[row], gamma);
        tw[k] = powf(g + (1.0f - g) * prev_w[row], gamma);
        sr += tr[k]; sw += tw[k];
    }
    sr = wave_reduce(sr);
    sw = wave_reduce(sw);
    if ((c & 63) == 0) { rg[wid] = sr; rm[wid] = sw; }
    __syncthreads();
    if (c == 0) {
        float a = 0.0f, b = 0.0f;
        #pragma unroll
        for (int i = 0; i < 16; ++i) { a += rg[i]; b += rm[i]; }
        bc[2] = 1.0f / a;   // 1/S_r
        bc[3] = 1.0f / b;   // 1/S_w
    }
    __syncthreads();
    const float isr = bc[2], isw = bc[3];
    #pragma unroll
    for (int k = 0; k < 8; ++k) {
        const int row = c + 1024 * k;
        const float wr = tr[k] * isr;
        ws[WN_OFF + row]     = wr;             // normalized, for K3
        d_out[MM + row]      = wr;             // read_weight output
        d_out[MM + NN + row] = tw[k] * isw;    // write_weight output
    }
}

// K3: the 128 MB pass (R2's proven shape). Grid (4, 256), block 256. Block (bx,by)
// covers f4-cols [bx*256,+256) x rows [by*32,+32). 4 pipeline groups of 8 independent
// float4 loads. Weights are pre-normalized by K2, so partial sums are final up to the
// cross-block reduction. Nontemporal loads: memory is read-once, don't thrash L2.
__global__ __launch_bounds__(256) void k_readvec(
    const float* __restrict__ memory, float* __restrict__ ws)
{
    __shared__ float tch[32];
    const int t = threadIdx.x;
    const int bx = blockIdx.x;      // 0..3
    const int by = blockIdx.y;      // 0..255
    const int row0 = by * 32;

    if (t < 32) tch[t] = ws[WN_OFF + row0 + t];
    __syncthreads();

    const int c4 = bx * 256 + t;    // float4 column, 0..1023
    const nt_f4* __restrict__ mem4 = (const nt_f4*)memory + (size_t)row0 * 1024 + c4;
    float ax = 0.0f, ay = 0.0f, az = 0.0f, aw = 0.0f;
    #pragma unroll
    for (int grp = 0; grp < 4; ++grp) {
        nt_f4 m[8];
        #pragma unroll
        for (int j = 0; j < 8; ++j)
            m[j] = __builtin_nontemporal_load(&mem4[(size_t)(grp * 8 + j) * 1024]);
        #pragma unroll
        for (int j = 0; j < 8; ++j) {
            const float w = tch[grp * 8 + j];
            ax += w * m[j].x; ay += w * m[j].y; az += w * m[j].z; aw += w * m[j].w;
        }
    }
    float4 acc; acc.x = ax; acc.y = ay; acc.z = az; acc.w = aw;
    ((float4*)(ws + P_OFF))[(size_t)by * 1024 + c4] = acc;
}

// K4: reduce partials -> read_vector. 64 blocks; block rb owns f4-cols [rb*16,+16).
// Thread (col = t&15, rg = t>>4): sum 16 partial rows; LDS reduce over 16 row-groups.
// No division -- weights were pre-normalized.
__global__ __launch_bounds__(256) void k_finalize(
    const float* __restrict__ ws, float* __restrict__ d_out)
{
    __shared__ float4 red[256];
    const int t = threadIdx.x, rb = blockIdx.x;
    const int col = t & 15;
    const int rg  = t >> 4;
    const int c4  = rb * 16 + col;              // 0..1023
    const float4* __restrict__ P4 = (const float4*)(ws + P_OFF);
    float4 s = {0.0f, 0.0f, 0.0f, 0.0f};
    #pragma unroll
    for (int k = 0; k < 16; ++k) {
        float4 v = P4[(size_t)(rg * 16 + k) * 1024 + c4];
        s.x += v.x; s.y += v.y; s.z += v.z; s.w += v.w;
    }
    red[t] = s;
    __syncthreads();
    if (t < 16) {
        float4 a = red[t];
        #pragma unroll
        for (int g2 = 1; g2 < 16; ++g2) {
            float4 v = red[g2 * 16 + t];
            a.x += v.x; a.y += v.y; a.z += v.z; a.w += v.w;
        }
        ((float4*)d_out)[rb * 16 + t] = a;      // read_vector
    }
}

extern "C" void kernel_launch(void* const* d_in, const int* in_sizes, int n_in,
                              void* d_out, int out_size, void* d_ws, size_t ws_size,
                              hipStream_t stream)
{
    const float* action = (const float*)d_in[0];
    const float* hidden = (const float*)d_in[1];
    const float* prev_r = (const float*)d_in[2];
    const float* prev_w = (const float*)d_in[3];
    const float* hprev  = (const float*)d_in[4];   // prev_controller_hidden
    const float* memory = (const float*)d_in[5];
    const float* W_ih   = (const float*)d_in[6];
    const float* W_hh   = (const float*)d_in[7];
    const float* b_ih   = (const float*)d_in[8];
    const float* b_hh   = (const float*)d_in[9];
    // d_in[10..19] provably unused: softmax over size-1 axis == 1 (kills W_read/W_write
    // and the memory-norm pass), circular-conv scalar cancels in sharpen (kills W_shift),
    // memory write is discarded (kills W_add/W_erase).
    const float* W_gamma = (const float*)d_in[20];
    const float* b_gamma = (const float*)d_in[21];
    const float* W_gate  = (const float*)d_in[22];
    const float* b_gate  = (const float*)d_in[23];

    float* ws  = (float*)d_ws;
    float* out = (float*)d_out;

    hipLaunchKernelGGL(k_gru_gates, dim3(3 * CC / 4), dim3(256), 0, stream,
                       action, hidden, W_ih, W_hh, b_ih, b_hh, hprev, ws);
    hipLaunchKernelGGL(k_gru_combine, dim3(1), dim3(1024), 0, stream,
                       hprev, prev_r, prev_w, W_gate, b_gate, W_gamma, b_gamma, ws, out);
    hipLaunchKernelGGL(k_readvec, dim3(4, 256), dim3(256), 0, stream,
                       memory, ws);
    hipLaunchKernelGGL(k_finalize, dim3(64), dim3(256), 0, stream,
                       ws, out);
}